// Round 16
// baseline (117.790 us; speedup 1.0000x reference)
//
#include <hip/hip_runtime.h>
#include <hip/hip_bf16.h>
#include <stdint.h>

// B=8, C=256, L=2048, DK=DV=256, KS=3, PAD=1
// conv-QKV as GEMM (bf16 MFMA), flash attention with swapped QK^T.
// R16: TRUE 4 blocks/CU — occupancy record shows the LDS pool behaves as
// ~128KB with 64KB-slot rounding (32KB->4 blocks [R4: 39%], 48KB->2 blocks
// [R13: 19.5% even with 1024 blocks]). So: single-buffer BOTH K and V
// (32KB total), kvh=8 -> 1024 blocks, keep 4 waves x 32q and the R11 engine.
// 3 barriers/kt (stage K after QK-barrier, V after PV-barrier).

typedef __bf16 bf16;
typedef __bf16 bf16x2 __attribute__((ext_vector_type(2)));
typedef __bf16 bf16x4 __attribute__((ext_vector_type(4)));
typedef __bf16 bf16x8 __attribute__((ext_vector_type(8)));
typedef float f32x4 __attribute__((ext_vector_type(4)));
typedef uint32_t u32x4 __attribute__((ext_vector_type(4)));
typedef __attribute__((address_space(1))) const uint32_t cu32_as1;
typedef __attribute__((address_space(3))) uint32_t u32_as3;

#define DEVI __device__ __forceinline__
#define LOG2E 1.44269504088896f

DEVI void async_copy16(const void* g, void* l) {
  __builtin_amdgcn_global_load_lds((cu32_as1*)g, (u32_as3*)l, 16, 0, 0);
}

DEVI void block_sync() {
  asm volatile("" ::: "memory");
  __builtin_amdgcn_sched_barrier(0);
  __builtin_amdgcn_s_barrier();
  __builtin_amdgcn_sched_barrier(0);
  asm volatile("" ::: "memory");
}

#define VMCNT(n) asm volatile("s_waitcnt vmcnt(" #n ")" ::: "memory")

// ---------------- prep: weights + bias ----------------
__global__ void prep_w(const float* __restrict__ Wq, const float* __restrict__ Wk,
                       const float* __restrict__ Wv, const float* __restrict__ bq,
                       const float* __restrict__ bk, const float* __restrict__ bv,
                       bf16* __restrict__ W2, float* __restrict__ biasA) {
  const float QSC = 0.0625f * LOG2E;
  int idx = blockIdx.x * 256 + threadIdx.x;
  if (idx < 768 * 768) {
    int o = idx / 768, kk = idx - o * 768;
    int ks = kk >> 8, c = kk & 255;
    const float* W = (o < 256) ? Wq : ((o < 512) ? Wk : Wv);
    int ol = o & 255;
    float w = W[ol * 768 + c * 3 + ks];
    if (o < 256) w *= QSC;
    W2[o * 768 + kk] = (bf16)w;
  }
  if (idx < 768) {
    float v;
    if (idx < 256) v = bq[idx] * QSC;
    else if (idx < 512) v = bk[idx - 256];
    else v = bv[idx - 512];
    biasA[idx] = v;
  }
}

// ---------------- prep: transpose x -> xTpad[b][l+1][c] ----------------
__global__ void prep_x(const float* __restrict__ x, bf16* __restrict__ xT) {
  __shared__ float tile[32][33];
  int bid = blockIdx.x;
  int lt = bid & 63, ct = (bid >> 6) & 7, b = bid >> 9;
  int t = threadIdx.x;
  int tl = t & 31, tc = t >> 5;
  const float* xb = x + (size_t)b * 256 * 2048;
#pragma unroll
  for (int i = 0; i < 4; ++i) {
    int c = ct * 32 + tc + i * 8;
    tile[tc + i * 8][tl] = xb[(size_t)c * 2048 + lt * 32 + tl];
  }
  __syncthreads();
  bf16* xTb = xT + (size_t)b * 2050 * 256;
#pragma unroll
  for (int i = 0; i < 4; ++i) {
    int l = lt * 32 + tc + i * 8;
    xTb[(size_t)(l + 1) * 256 + ct * 32 + tl] = (bf16)tile[tl][tc + i * 8];
  }
  if (lt == 0 && t < 32) xTb[ct * 32 + t] = (bf16)0.f;
  if (lt == 63 && t < 32) xTb[(size_t)2049 * 256 + ct * 32 + t] = (bf16)0.f;
}

// ---------------- conv as MFMA GEMM (unchanged) ----------------
__launch_bounds__(256, 2)
__global__ void conv_gemm(const bf16* __restrict__ W2, const bf16* __restrict__ xT,
                          const float* __restrict__ biasA, bf16* __restrict__ QT,
                          bf16* __restrict__ KT, bf16* __restrict__ V) {
  __shared__ bf16 Alds[128 * 64];
  __shared__ bf16 Blds[128 * 64];
  const int t = threadIdx.x;
  const int w = t >> 6, lane = t & 63;
  const int g = lane >> 4, lr = lane & 15;
  const int wr = w >> 1, wc = w & 1;
  const int bid = blockIdx.x;
  const int b = bid & 7;
  const int rest = bid >> 3;
  const int ot = rest % 6;
  const int lt = rest / 6;
  const int l0 = lt * 128;

  const bf16* xTb = xT + (size_t)b * 2050 * 256;
  const bf16* Ab = W2 + (size_t)(ot * 128) * 768;

  const int srow = t >> 3;
  const int scb = ((t & 7) * 16) ^ ((srow & 7) << 4);

  f32x4 acc[4][4];
#pragma unroll
  for (int i = 0; i < 4; ++i)
#pragma unroll
    for (int j = 0; j < 4; ++j) acc[i][j] = (f32x4){0.f, 0.f, 0.f, 0.f};

  for (int step = 0; step < 12; ++step) {
    const int kk = step * 64;
    const int ks = kk >> 8;
    const int c0 = kk & 255;
    const bf16* As = Ab + kk + (scb >> 1);
    const bf16* Bs = xTb + (size_t)(l0 + ks) * 256 + c0 + (scb >> 1);
#pragma unroll
    for (int i = 0; i < 4; ++i) {
      const int row = srow + i * 32;
      async_copy16(As + (size_t)row * 768, (char*)Alds + w * 1024 + i * 4096);
      async_copy16(Bs + (size_t)row * 256, (char*)Blds + w * 1024 + i * 4096);
    }
    asm volatile("s_waitcnt vmcnt(0)" ::: "memory");
    __syncthreads();
#pragma unroll
    for (int sub = 0; sub < 2; ++sub) {
      bf16x8 af[4], bfr[4];
#pragma unroll
      for (int mf = 0; mf < 4; ++mf) {
        const int row = wr * 64 + mf * 16 + lr;
        const int cb = (sub * 64 + g * 16) ^ ((row & 7) << 4);
        af[mf] = *(const bf16x8*)((const char*)Alds + row * 128 + cb);
      }
#pragma unroll
      for (int nf = 0; nf < 4; ++nf) {
        const int row = wc * 64 + nf * 16 + lr;
        const int cb = (sub * 64 + g * 16) ^ ((row & 7) << 4);
        bfr[nf] = *(const bf16x8*)((const char*)Blds + row * 128 + cb);
      }
#pragma unroll
      for (int mf = 0; mf < 4; ++mf)
#pragma unroll
        for (int nf = 0; nf < 4; ++nf)
          acc[mf][nf] = __builtin_amdgcn_mfma_f32_16x16x32_bf16(af[mf], bfr[nf], acc[mf][nf], 0, 0, 0);
    }
    __syncthreads();
  }

  const int obase = ot * 128 + wr * 64;
  const int lbase = l0 + wc * 64;
  if (ot < 4) {
    bf16* dst = ((ot < 2) ? QT : KT) + (size_t)b * 2048 * 256;
#pragma unroll
    for (int mf = 0; mf < 4; ++mf) {
      const int og = obase + mf * 16 + g * 4;
      float bb[4];
#pragma unroll
      for (int r = 0; r < 4; ++r) bb[r] = biasA[og + r];
#pragma unroll
      for (int nf = 0; nf < 4; ++nf) {
        const int l = lbase + nf * 16 + lr;
        bf16x4 pk;
#pragma unroll
        for (int r = 0; r < 4; ++r) pk[r] = (bf16)(acc[mf][nf][r] + bb[r]);
        *(bf16x4*)(dst + (size_t)l * 256 + (og & 255)) = pk;
      }
    }
  } else {
    bf16* dst = V + (size_t)b * 256 * 2048;
#pragma unroll
    for (int mf = 0; mf < 4; ++mf) {
      const int og = obase + mf * 16 + g * 4;
      float bb[4];
#pragma unroll
      for (int r = 0; r < 4; ++r) bb[r] = biasA[og + r];
      const int ov = og - 512;
#pragma unroll
      for (int nf = 0; nf < 4; ++nf) {
        const int l = lbase + nf * 16 + lr;
#pragma unroll
        for (int r = 0; r < 4; ++r)
          dst[(size_t)(ov + r) * 2048 + l] = (bf16)(acc[mf][nf][r] + bb[r]);
      }
    }
  }
}

// ---------------- flash attention (R16: 32KB LDS, 4 blocks/CU) ----------------
// 1024 blocks = b(8) x kvh(8) x qt(16); 256 threads = 4 waves, wave owns 32 q.
// Block = 128 q x 256 keys (8 tiles of 32). K and V both SINGLE-buffered
// (16KB each); 3 barriers/kt: A (loads landed), after-QK (stage K(kt+1)),
// after-PV (stage V(kt+1)). LDS 32KB -> 4 blocks/CU, 16 waves/CU.
// K LDS: [32 rows][512B], phys slot = logical ^ (row&31)
// V LDS: [128 rows][128B], V[d][k] -> row d>>1, byteL (d&1)*64+k*2, slot ^ (row&7)
__launch_bounds__(256, 2)
__global__ void attn(const bf16* __restrict__ QT, const bf16* __restrict__ KT,
                     const bf16* __restrict__ V, bf16* __restrict__ Opart,
                     float* __restrict__ Sl) {
  __shared__ bf16 Klds[32 * 256];   // 16 KB
  __shared__ bf16 Vlds[128 * 64];   // 16 KB
  const int t = threadIdx.x;
  const int w = t >> 6, lane = t & 63;
  const int g = lane >> 4, lr = lane & 15;
  const int bid = blockIdx.x;
  const int b = bid & 7;
  const int kvh = (bid >> 3) & 7;
  const int qt = bid >> 6;              // 0..15
  const int q0w = qt * 128 + w * 32;
  const int kb0 = kvh * 256;
  const bf16* QTb = QT + (size_t)b * 2048 * 256;
  const bf16* KTb = KT + (size_t)b * 2048 * 256;
  const bf16* Vb = V + (size_t)b * 256 * 2048;

  auto stageK = [&](int kt) {
#pragma unroll
    for (int i = 0; i < 4; ++i) {
      const int row = i * 8 + (t >> 5);
      const int col = ((t & 31) ^ row) * 8;
      const bf16* src = KTb + (size_t)(kb0 + kt * 32 + row) * 256 + col;
      async_copy16(src, (char*)Klds + i * 4096 + t * 16);
    }
  };
  auto stageV = [&](int kt) {
#pragma unroll
    for (int i = 0; i < 4; ++i) {
      const int row = i * 32 + (t >> 3);
      const int ls = (t & 7) ^ (row & 7);
      const int d = row * 2 + (ls >> 2);
      const int k0 = (ls & 3) * 8;
      const bf16* src = Vb + (size_t)d * 2048 + kb0 + kt * 32 + k0;
      async_copy16(src, (char*)Vlds + i * 4096 + t * 16);
    }
  };

  // Q in registers: q = q0w + qfr*16 + lr, d-chunk = ds*32 + g*8
  bf16x8 qreg[2][8];
#pragma unroll
  for (int qfr = 0; qfr < 2; ++qfr)
#pragma unroll
    for (int ds = 0; ds < 8; ++ds)
      qreg[qfr][ds] = *(const bf16x8*)(QTb + (size_t)(q0w + qfr * 16 + lr) * 256 + ds * 32 + g * 8);

  f32x4 oacc[16][2];
#pragma unroll
  for (int i = 0; i < 16; ++i) {
    oacc[i][0] = (f32x4){0.f, 0.f, 0.f, 0.f};
    oacc[i][1] = (f32x4){0.f, 0.f, 0.f, 0.f};
  }
  float l_acc[2] = {0.f, 0.f};   // lane-local partial softmax denominators

  // prologue: K(0), V(0)
  stageK(0);
  stageV(0);

  for (int kt = 0; kt < 8; ++kt) {
    VMCNT(0);          // K(kt) and V(kt) landed (this thread's loads)
    block_sync();      // A: everyone's tile kt landed; K/V buffers readable

    // ---- QK^T (swapped): sT[kfr][qfr] = S[k = kt*32+kfr*16+g*4+r][q = qfr*16+lr]
    f32x4 sT[2][2];
#pragma unroll
    for (int kfr = 0; kfr < 2; ++kfr)
#pragma unroll
      for (int qfr = 0; qfr < 2; ++qfr) sT[kfr][qfr] = (f32x4){0.f, 0.f, 0.f, 0.f};
    __builtin_amdgcn_s_setprio(1);
#pragma unroll
    for (int ds = 0; ds < 8; ++ds) {
      bf16x8 kf[2];
#pragma unroll
      for (int kfr = 0; kfr < 2; ++kfr) {
        const int row = kfr * 16 + lr;
        kf[kfr] = *(const bf16x8*)((const char*)Klds + row * 512 +
                                   (((ds * 4 + g) ^ row) * 16));
      }
#pragma unroll
      for (int kfr = 0; kfr < 2; ++kfr)
#pragma unroll
        for (int qfr = 0; qfr < 2; ++qfr)
          sT[kfr][qfr] = __builtin_amdgcn_mfma_f32_16x16x32_bf16(kf[kfr], qreg[qfr][ds], sT[kfr][qfr], 0, 0, 0);
    }
    __builtin_amdgcn_s_setprio(0);
    block_sync();                  // K consumed by all waves
    if (kt < 7) stageK(kt + 1);    // K(kt+1) latency hides under softmax+pack+PV

    // ---- P = exp2(S) (no max-stabilization; lane-local l accumulation)
#pragma unroll
    for (int kfr = 0; kfr < 2; ++kfr)
#pragma unroll
      for (int qfr = 0; qfr < 2; ++qfr)
#pragma unroll
        for (int r = 0; r < 4; ++r) {
          float pe = __builtin_exp2f(sT[kfr][qfr][r]);
          sT[kfr][qfr][r] = pe;
          l_acc[qfr] += pe;
        }

    // ---- P route to PV B-operand (in-register, per qfr)
    bf16x8 pB[2];
#pragma unroll
    for (int qfr = 0; qfr < 2; ++qfr) {
      uint32_t wq[2][2];
#pragma unroll
      for (int kfr = 0; kfr < 2; ++kfr)
#pragma unroll
        for (int pp = 0; pp < 2; ++pp) {
          bf16x2 pr;
          pr[0] = (bf16)sT[kfr][qfr][2 * pp];
          pr[1] = (bf16)sT[kfr][qfr][2 * pp + 1];
          wq[kfr][pp] = __builtin_bit_cast(uint32_t, pr);
        }
      uint32_t bw[4];
#pragma unroll
      for (int j = 0; j < 4; ++j) {
        const int srcLane = ((g & 1) * 2 + (j >> 1)) * 16 + lr;
        const uint32_t a = (uint32_t)__shfl((int)wq[0][j & 1], srcLane, 64);
        const uint32_t bb = (uint32_t)__shfl((int)wq[1][j & 1], srcLane, 64);
        bw[j] = (lane < 32) ? a : bb;
      }
      u32x4 v4 = {bw[0], bw[1], bw[2], bw[3]};
      pB[qfr] = __builtin_bit_cast(bf16x8, v4);
    }

    // ---- PV: oacc[dfr][qfr] += V[d][k] * P[k][q]
    __builtin_amdgcn_s_setprio(1);
#pragma unroll
    for (int dfr = 0; dfr < 16; ++dfr) {
      const int row = dfr * 8 + (lr >> 1);
      bf16x8 vf = *(const bf16x8*)((const char*)Vlds + row * 128 +
                                   ((((lr & 1) * 4 + g) ^ ((lr >> 1) & 7)) * 16));
      oacc[dfr][0] = __builtin_amdgcn_mfma_f32_16x16x32_bf16(vf, pB[0], oacc[dfr][0], 0, 0, 0);
      oacc[dfr][1] = __builtin_amdgcn_mfma_f32_16x16x32_bf16(vf, pB[1], oacc[dfr][1], 0, 0, 0);
    }
    __builtin_amdgcn_s_setprio(0);
    block_sync();                  // V consumed by all waves
    if (kt < 7) stageV(kt + 1);    // V(kt+1); covered by 4-block TLP
  }

  // ---- epilogue: reduce l across the 4 k-groups (lanes lr, lr+16, lr+32, lr+48)
#pragma unroll
  for (int qfr = 0; qfr < 2; ++qfr) {
    float rv = l_acc[qfr];
    rv += __shfl_xor(rv, 16, 64);
    rv += __shfl_xor(rv, 32, 64);
    l_acc[qfr] = rv;
  }

  // ---- store partial O (bf16, [q][d]) + l
  bf16* Op = Opart + (size_t)bid * 128 * 256;
#pragma unroll
  for (int qfr = 0; qfr < 2; ++qfr) {
    const int ql = w * 32 + qfr * 16 + lr;
#pragma unroll
    for (int dfr = 0; dfr < 16; ++dfr) {
      const int d0 = dfr * 16 + g * 4;
      bf16x4 pk;
#pragma unroll
      for (int r = 0; r < 4; ++r) pk[r] = (bf16)oacc[dfr][qfr][r];
      *(bf16x4*)(Op + (size_t)ql * 256 + d0) = pk;
    }
    if (g == 0) Sl[bid * 128 + ql] = l_acc[qfr];
  }
}

// ---------------- merge 8 KV-split partials -> H (vectorized, coalesced) ----------------
// 512 blocks = b(8) x qt(16) x qc(4); 256 threads. Each handles 32 q x 256 d.
// attn block id = b + 8*kvh + 64*qt. 16B bf16x8 Opart loads.
__launch_bounds__(256)
__global__ void merge_p(const bf16* __restrict__ Opart, const float* __restrict__ Sl,
                        float* __restrict__ H) {
  __shared__ float Ocomb[32][257];
  const int bid = blockIdx.x;
  const int b = bid & 7;
  const int qt = (bid >> 3) & 15;
  const int qc = bid >> 7;
  const int t = threadIdx.x;
  const int g2 = t >> 5, lane2 = t & 31;
  float* Hb = H + (size_t)b * 256 * 2048 + qt * 128 + qc * 32;

#pragma unroll
  for (int qb = 0; qb < 4; ++qb) {
    const int qq = qb * 8 + g2;
    const int ql = qc * 32 + qq;
    float wsum = 0.f;
    float o[8];
#pragma unroll
    for (int j = 0; j < 8; ++j) o[j] = 0.f;
#pragma unroll
    for (int kvh = 0; kvh < 8; ++kvh) {
      const int blk = b + 8 * kvh + 64 * qt;
      wsum += Sl[blk * 128 + ql];
      bf16x8 v = *(const bf16x8*)(Opart + ((size_t)blk * 128 + ql) * 256 + lane2 * 8);
#pragma unroll
      for (int j = 0; j < 8; ++j) o[j] += (float)v[j];
    }
    const float inv = 1.f / wsum;
#pragma unroll
    for (int j = 0; j < 8; ++j) Ocomb[qq][lane2 * 8 + j] = o[j] * inv;
  }
  __syncthreads();
  const int q = t & 31;
  const int dbase = (t >> 5) * 32;
#pragma unroll
  for (int j = 0; j < 32; ++j) {
    const int d = dbase + j;
    Hb[(size_t)d * 2048 + q] = Ocomb[q][d];
  }
}

extern "C" void kernel_launch(void* const* d_in, const int* in_sizes, int n_in,
                              void* d_out, int out_size, void* d_ws, size_t ws_size,
                              hipStream_t stream) {
  (void)in_sizes; (void)n_in; (void)out_size; (void)ws_size;
  const float* x = (const float*)d_in[0];
  const float* Wq = (const float*)d_in[1];
  const float* bq = (const float*)d_in[2];
  const float* Wk = (const float*)d_in[3];
  const float* bk = (const float*)d_in[4];
  const float* Wv = (const float*)d_in[5];
  const float* bv = (const float*)d_in[6];
  char* ws = (char*)d_ws;
  bf16* xT = (bf16*)(ws + 0);                 // 8,396,800
  bf16* W2 = (bf16*)(ws + 8396800);           // 1,179,648
  float* biasA = (float*)(ws + 9576448);      // 3,072 (+pad)
  bf16* QT = (bf16*)(ws + 9580544);           // 8,388,608
  bf16* KT = (bf16*)(ws + 17969152);          // 8,388,608
  bf16* V = (bf16*)(ws + 26357760);           // 8,388,608
  bf16* Opart = (bf16*)(ws + 34746368);       // 1024*128*256*2 = 67,108,864
  float* Sl = (float*)(ws + 101855232);       // 1024*128*4 = 524,288 (end ~102.4MB)
  float* H = (float*)d_out;

  prep_w<<<dim3(2304), dim3(256), 0, stream>>>(Wq, Wk, Wv, bq, bk, bv, W2, biasA);
  prep_x<<<dim3(4096), dim3(256), 0, stream>>>(x, xT);
  conv_gemm<<<dim3(768), dim3(256), 0, stream>>>(W2, xT, biasA, QT, KT, V);
  attn<<<dim3(1024), dim3(256), 0, stream>>>(QT, KT, V, Opart, Sl);
  merge_p<<<dim3(512), dim3(256), 0, stream>>>(Opart, Sl, H);
}

// Round 17
// 108.727 us; speedup vs baseline: 1.0834x; 1.0834x over previous
//
#include <hip/hip_runtime.h>
#include <hip/hip_bf16.h>
#include <stdint.h>

// B=8, C=256, L=2048, DK=DV=256, KS=3, PAD=1
// conv-QKV as GEMM (bf16 MFMA), flash attention with swapped QK^T.
// R17: consolidation — attn = R11 verbatim (best measured 69.3us: setprio,
// pinned sync, K dbuf + V single 48KB, VMCNT(4)); merge_p = R15 vectorized;
// prep_x rewritten so fp32 reads AND bf16 writes are 128B/wave contiguous.

typedef __bf16 bf16;
typedef __bf16 bf16x2 __attribute__((ext_vector_type(2)));
typedef __bf16 bf16x4 __attribute__((ext_vector_type(4)));
typedef __bf16 bf16x8 __attribute__((ext_vector_type(8)));
typedef float f32x4 __attribute__((ext_vector_type(4)));
typedef uint32_t u32x4 __attribute__((ext_vector_type(4)));
typedef __attribute__((address_space(1))) const uint32_t cu32_as1;
typedef __attribute__((address_space(3))) uint32_t u32_as3;

#define DEVI __device__ __forceinline__
#define LOG2E 1.44269504088896f

DEVI void async_copy16(const void* g, void* l) {
  __builtin_amdgcn_global_load_lds((cu32_as1*)g, (u32_as3*)l, 16, 0, 0);
}

DEVI void block_sync() {
  asm volatile("" ::: "memory");
  __builtin_amdgcn_sched_barrier(0);
  __builtin_amdgcn_s_barrier();
  __builtin_amdgcn_sched_barrier(0);
  asm volatile("" ::: "memory");
}

#define VMCNT(n) asm volatile("s_waitcnt vmcnt(" #n ")" ::: "memory")

// ---------------- prep: weights + bias ----------------
__global__ void prep_w(const float* __restrict__ Wq, const float* __restrict__ Wk,
                       const float* __restrict__ Wv, const float* __restrict__ bq,
                       const float* __restrict__ bk, const float* __restrict__ bv,
                       bf16* __restrict__ W2, float* __restrict__ biasA) {
  const float QSC = 0.0625f * LOG2E;
  int idx = blockIdx.x * 256 + threadIdx.x;
  if (idx < 768 * 768) {
    int o = idx / 768, kk = idx - o * 768;
    int ks = kk >> 8, c = kk & 255;
    const float* W = (o < 256) ? Wq : ((o < 512) ? Wk : Wv);
    int ol = o & 255;
    float w = W[ol * 768 + c * 3 + ks];
    if (o < 256) w *= QSC;
    W2[o * 768 + kk] = (bf16)w;
  }
  if (idx < 768) {
    float v;
    if (idx < 256) v = bq[idx] * QSC;
    else if (idx < 512) v = bk[idx - 256];
    else v = bv[idx - 512];
    biasA[idx] = v;
  }
}

// ---------------- prep: transpose x -> xTpad[b][l+1][c] (fully coalesced) ------
// 2048 blocks = b(8) x lt(64) x ct(4); 256 threads. Tile = 64c x 32l.
// Reads: lane sweeps l (128B fp32/wave). Writes: lane sweeps c (128B bf16/wave).
__global__ void prep_x(const float* __restrict__ x, bf16* __restrict__ xT) {
  __shared__ float tile[64][33];
  const int bid = blockIdx.x;
  const int b = bid >> 8;
  const int rest = bid & 255;
  const int ct = rest & 3;        // 4 tiles of 64 c
  const int lt = rest >> 2;       // 64 tiles of 32 l
  const int c0 = ct * 64, l0 = lt * 32;
  const int t = threadIdx.x;
  const float* xb = x + (size_t)b * 256 * 2048;
  // read: c = c0 + (t>>5) + i*8, l = l0 + (t&31)
#pragma unroll
  for (int i = 0; i < 8; ++i) {
    const int cc = (t >> 5) + i * 8;
    tile[cc][t & 31] = xb[(size_t)(c0 + cc) * 2048 + l0 + (t & 31)];
  }
  __syncthreads();
  bf16* xTb = xT + (size_t)b * 2050 * 256;
  // write: c = c0 + (t&63), l = l0 + (t>>6) + j*4
#pragma unroll
  for (int j = 0; j < 8; ++j) {
    const int ll = (t >> 6) + j * 4;
    xTb[(size_t)(l0 + ll + 1) * 256 + c0 + (t & 63)] = (bf16)tile[t & 63][ll];
  }
  // pad rows 0 and 2049
  if (lt == 0 && t < 64) xTb[c0 + t] = (bf16)0.f;
  if (lt == 63 && t < 64) xTb[(size_t)2049 * 256 + c0 + t] = (bf16)0.f;
}

// ---------------- conv as MFMA GEMM (unchanged) ----------------
__launch_bounds__(256, 2)
__global__ void conv_gemm(const bf16* __restrict__ W2, const bf16* __restrict__ xT,
                          const float* __restrict__ biasA, bf16* __restrict__ QT,
                          bf16* __restrict__ KT, bf16* __restrict__ V) {
  __shared__ bf16 Alds[128 * 64];
  __shared__ bf16 Blds[128 * 64];
  const int t = threadIdx.x;
  const int w = t >> 6, lane = t & 63;
  const int g = lane >> 4, lr = lane & 15;
  const int wr = w >> 1, wc = w & 1;
  const int bid = blockIdx.x;
  const int b = bid & 7;
  const int rest = bid >> 3;
  const int ot = rest % 6;
  const int lt = rest / 6;
  const int l0 = lt * 128;

  const bf16* xTb = xT + (size_t)b * 2050 * 256;
  const bf16* Ab = W2 + (size_t)(ot * 128) * 768;

  const int srow = t >> 3;
  const int scb = ((t & 7) * 16) ^ ((srow & 7) << 4);

  f32x4 acc[4][4];
#pragma unroll
  for (int i = 0; i < 4; ++i)
#pragma unroll
    for (int j = 0; j < 4; ++j) acc[i][j] = (f32x4){0.f, 0.f, 0.f, 0.f};

  for (int step = 0; step < 12; ++step) {
    const int kk = step * 64;
    const int ks = kk >> 8;
    const int c0 = kk & 255;
    const bf16* As = Ab + kk + (scb >> 1);
    const bf16* Bs = xTb + (size_t)(l0 + ks) * 256 + c0 + (scb >> 1);
#pragma unroll
    for (int i = 0; i < 4; ++i) {
      const int row = srow + i * 32;
      async_copy16(As + (size_t)row * 768, (char*)Alds + w * 1024 + i * 4096);
      async_copy16(Bs + (size_t)row * 256, (char*)Blds + w * 1024 + i * 4096);
    }
    asm volatile("s_waitcnt vmcnt(0)" ::: "memory");
    __syncthreads();
#pragma unroll
    for (int sub = 0; sub < 2; ++sub) {
      bf16x8 af[4], bfr[4];
#pragma unroll
      for (int mf = 0; mf < 4; ++mf) {
        const int row = wr * 64 + mf * 16 + lr;
        const int cb = (sub * 64 + g * 16) ^ ((row & 7) << 4);
        af[mf] = *(const bf16x8*)((const char*)Alds + row * 128 + cb);
      }
#pragma unroll
      for (int nf = 0; nf < 4; ++nf) {
        const int row = wc * 64 + nf * 16 + lr;
        const int cb = (sub * 64 + g * 16) ^ ((row & 7) << 4);
        bfr[nf] = *(const bf16x8*)((const char*)Blds + row * 128 + cb);
      }
#pragma unroll
      for (int mf = 0; mf < 4; ++mf)
#pragma unroll
        for (int nf = 0; nf < 4; ++nf)
          acc[mf][nf] = __builtin_amdgcn_mfma_f32_16x16x32_bf16(af[mf], bfr[nf], acc[mf][nf], 0, 0, 0);
    }
    __syncthreads();
  }

  const int obase = ot * 128 + wr * 64;
  const int lbase = l0 + wc * 64;
  if (ot < 4) {
    bf16* dst = ((ot < 2) ? QT : KT) + (size_t)b * 2048 * 256;
#pragma unroll
    for (int mf = 0; mf < 4; ++mf) {
      const int og = obase + mf * 16 + g * 4;
      float bb[4];
#pragma unroll
      for (int r = 0; r < 4; ++r) bb[r] = biasA[og + r];
#pragma unroll
      for (int nf = 0; nf < 4; ++nf) {
        const int l = lbase + nf * 16 + lr;
        bf16x4 pk;
#pragma unroll
        for (int r = 0; r < 4; ++r) pk[r] = (bf16)(acc[mf][nf][r] + bb[r]);
        *(bf16x4*)(dst + (size_t)l * 256 + (og & 255)) = pk;
      }
    }
  } else {
    bf16* dst = V + (size_t)b * 256 * 2048;
#pragma unroll
    for (int mf = 0; mf < 4; ++mf) {
      const int og = obase + mf * 16 + g * 4;
      float bb[4];
#pragma unroll
      for (int r = 0; r < 4; ++r) bb[r] = biasA[og + r];
      const int ov = og - 512;
#pragma unroll
      for (int nf = 0; nf < 4; ++nf) {
        const int l = lbase + nf * 16 + lr;
#pragma unroll
        for (int r = 0; r < 4; ++r)
          dst[(size_t)(ov + r) * 2048 + l] = (bf16)(acc[mf][nf][r] + bb[r]);
      }
    }
  }
}

// ---------------- flash attention (R11 verbatim) ----------------
// 512 blocks = b(8) x kvh(4) x qt(16); 256 threads = 4 waves, wave owns 32 q.
// Keys [kvh*512 .. +512) in 16 tiles of 32. K double-buffered (staged 2 ahead),
// V single-buffered (staged 1 ahead). 2 barriers/kt. LDS 48KB. ~128 VGPR.
// K LDS: [p][32 rows][512B], phys slot = logical ^ (row&31)
// V LDS: [128 rows][128B], V[d][k] -> row d>>1, byteL (d&1)*64+k*2, slot ^ (row&7)
__launch_bounds__(256, 2)
__global__ void attn(const bf16* __restrict__ QT, const bf16* __restrict__ KT,
                     const bf16* __restrict__ V, bf16* __restrict__ Opart,
                     float* __restrict__ Sl) {
  __shared__ bf16 Klds[2 * 32 * 256];   // 32 KB
  __shared__ bf16 Vlds[128 * 64];       // 16 KB (single buffer)
  const int t = threadIdx.x;
  const int w = t >> 6, lane = t & 63;
  const int g = lane >> 4, lr = lane & 15;
  const int bid = blockIdx.x;
  const int b = bid & 7;
  const int kvh = (bid >> 3) & 3;
  const int qt = bid >> 5;
  const int q0w = qt * 128 + w * 32;
  const int kb0 = kvh * 512;
  const bf16* QTb = QT + (size_t)b * 2048 * 256;
  const bf16* KTb = KT + (size_t)b * 2048 * 256;
  const bf16* Vb = V + (size_t)b * 256 * 2048;

  auto stageK = [&](int kt, int p) {
#pragma unroll
    for (int i = 0; i < 4; ++i) {
      const int row = i * 8 + (t >> 5);
      const int col = ((t & 31) ^ row) * 8;
      const bf16* src = KTb + (size_t)(kb0 + kt * 32 + row) * 256 + col;
      async_copy16(src, (char*)Klds + p * 16384 + i * 4096 + t * 16);
    }
  };
  auto stageV = [&](int kt) {
#pragma unroll
    for (int i = 0; i < 4; ++i) {
      const int row = i * 32 + (t >> 3);
      const int ls = (t & 7) ^ (row & 7);
      const int d = row * 2 + (ls >> 2);
      const int k0 = (ls & 3) * 8;
      const bf16* src = Vb + (size_t)d * 2048 + kb0 + kt * 32 + k0;
      async_copy16(src, (char*)Vlds + i * 4096 + t * 16);
    }
  };

  // Q in registers: q = q0w + qfr*16 + lr, d-chunk = ds*32 + g*8
  bf16x8 qreg[2][8];
#pragma unroll
  for (int qfr = 0; qfr < 2; ++qfr)
#pragma unroll
    for (int ds = 0; ds < 8; ++ds)
      qreg[qfr][ds] = *(const bf16x8*)(QTb + (size_t)(q0w + qfr * 16 + lr) * 256 + ds * 32 + g * 8);

  f32x4 oacc[16][2];
#pragma unroll
  for (int i = 0; i < 16; ++i) {
    oacc[i][0] = (f32x4){0.f, 0.f, 0.f, 0.f};
    oacc[i][1] = (f32x4){0.f, 0.f, 0.f, 0.f};
  }
  float l_acc[2] = {0.f, 0.f};   // lane-local partial softmax denominators

  // prologue: V(0) first, then K(0), K(1)  (issue order matters for VMCNT)
  stageV(0);
  stageK(0, 0);
  stageK(1, 1);

  for (int kt = 0; kt < 16; ++kt) {
    const int p = kt & 1;
    if (kt == 15) { VMCNT(0); } else { VMCNT(4); }  // K(kt), V(kt) landed
    block_sync();                                    // A: everyone's tile kt landed

    // ---- QK^T (swapped): sT[kfr][qfr] = S[k = kt*32+kfr*16+g*4+r][q = qfr*16+lr]
    f32x4 sT[2][2];
#pragma unroll
    for (int kfr = 0; kfr < 2; ++kfr)
#pragma unroll
      for (int qfr = 0; qfr < 2; ++qfr) sT[kfr][qfr] = (f32x4){0.f, 0.f, 0.f, 0.f};
    __builtin_amdgcn_s_setprio(1);
#pragma unroll
    for (int ds = 0; ds < 8; ++ds) {
      bf16x8 kf[2];
#pragma unroll
      for (int kfr = 0; kfr < 2; ++kfr) {
        const int row = kfr * 16 + lr;
        kf[kfr] = *(const bf16x8*)((const char*)Klds + p * 16384 + row * 512 +
                                   (((ds * 4 + g) ^ row) * 16));
      }
#pragma unroll
      for (int kfr = 0; kfr < 2; ++kfr)
#pragma unroll
        for (int qfr = 0; qfr < 2; ++qfr)
          sT[kfr][qfr] = __builtin_amdgcn_mfma_f32_16x16x32_bf16(kf[kfr], qreg[qfr][ds], sT[kfr][qfr], 0, 0, 0);
    }
    __builtin_amdgcn_s_setprio(0);

    // ---- P = exp2(S) (no max-stabilization; lane-local l accumulation)
#pragma unroll
    for (int kfr = 0; kfr < 2; ++kfr)
#pragma unroll
      for (int qfr = 0; qfr < 2; ++qfr)
#pragma unroll
        for (int r = 0; r < 4; ++r) {
          float pe = __builtin_exp2f(sT[kfr][qfr][r]);
          sT[kfr][qfr][r] = pe;
          l_acc[qfr] += pe;
        }

    // ---- P route to PV B-operand (in-register, per qfr)
    bf16x8 pB[2];
#pragma unroll
    for (int qfr = 0; qfr < 2; ++qfr) {
      uint32_t wq[2][2];
#pragma unroll
      for (int kfr = 0; kfr < 2; ++kfr)
#pragma unroll
        for (int pp = 0; pp < 2; ++pp) {
          bf16x2 pr;
          pr[0] = (bf16)sT[kfr][qfr][2 * pp];
          pr[1] = (bf16)sT[kfr][qfr][2 * pp + 1];
          wq[kfr][pp] = __builtin_bit_cast(uint32_t, pr);
        }
      uint32_t bw[4];
#pragma unroll
      for (int j = 0; j < 4; ++j) {
        const int srcLane = ((g & 1) * 2 + (j >> 1)) * 16 + lr;
        const uint32_t a = (uint32_t)__shfl((int)wq[0][j & 1], srcLane, 64);
        const uint32_t bb = (uint32_t)__shfl((int)wq[1][j & 1], srcLane, 64);
        bw[j] = (lane < 32) ? a : bb;
      }
      u32x4 v4 = {bw[0], bw[1], bw[2], bw[3]};
      pB[qfr] = __builtin_bit_cast(bf16x8, v4);
    }

    // ---- PV: oacc[dfr][qfr] += V[d][k] * P[k][q]
    __builtin_amdgcn_s_setprio(1);
#pragma unroll
    for (int dfr = 0; dfr < 16; ++dfr) {
      const int row = dfr * 8 + (lr >> 1);
      bf16x8 vf = *(const bf16x8*)((const char*)Vlds + row * 128 +
                                   ((((lr & 1) * 4 + g) ^ ((lr >> 1) & 7)) * 16));
      oacc[dfr][0] = __builtin_amdgcn_mfma_f32_16x16x32_bf16(vf, pB[0], oacc[dfr][0], 0, 0, 0);
      oacc[dfr][1] = __builtin_amdgcn_mfma_f32_16x16x32_bf16(vf, pB[1], oacc[dfr][1], 0, 0, 0);
    }
    __builtin_amdgcn_s_setprio(0);
    block_sync();                       // B: all waves done reading Klds[p], Vlds
    if (kt < 15) stageV(kt + 1);        // V(kt+1) hidden under next QK+softmax
    if (kt < 14) stageK(kt + 2, p);     // K(kt+2) into freed buffer p
  }

  // ---- epilogue: reduce l across the 4 k-groups (lanes lr, lr+16, lr+32, lr+48)
#pragma unroll
  for (int qfr = 0; qfr < 2; ++qfr) {
    float rv = l_acc[qfr];
    rv += __shfl_xor(rv, 16, 64);
    rv += __shfl_xor(rv, 32, 64);
    l_acc[qfr] = rv;
  }

  // ---- store partial O (bf16, [q][d]) + l
  bf16* Op = Opart + (size_t)bid * 128 * 256;
#pragma unroll
  for (int qfr = 0; qfr < 2; ++qfr) {
    const int ql = w * 32 + qfr * 16 + lr;
#pragma unroll
    for (int dfr = 0; dfr < 16; ++dfr) {
      const int d0 = dfr * 16 + g * 4;
      bf16x4 pk;
#pragma unroll
      for (int r = 0; r < 4; ++r) pk[r] = (bf16)oacc[dfr][qfr][r];
      *(bf16x4*)(Op + (size_t)ql * 256 + d0) = pk;
    }
    if (g == 0) Sl[bid * 128 + ql] = l_acc[qfr];
  }
}

// ---------------- merge 4 KV-split partials -> H (vectorized, coalesced) ----------------
// 512 blocks = b(8) x qt(16) x qc(4); 256 threads. Each handles 32 q x 256 d.
// 16B bf16x8 Opart loads (8 groups of 32 lanes; group = q row, lane = 8-d chunk).
__launch_bounds__(256)
__global__ void merge_p(const bf16* __restrict__ Opart, const float* __restrict__ Sl,
                        float* __restrict__ H) {
  __shared__ float Ocomb[32][257];
  const int bid = blockIdx.x;
  const int b = bid & 7;
  const int qt = (bid >> 3) & 15;
  const int qc = bid >> 7;
  const int t = threadIdx.x;
  const int g2 = t >> 5, lane2 = t & 31;
  float* Hb = H + (size_t)b * 256 * 2048 + qt * 128 + qc * 32;

#pragma unroll
  for (int qb = 0; qb < 4; ++qb) {
    const int qq = qb * 8 + g2;
    const int ql = qc * 32 + qq;
    float wsum = 0.f;
    float o[8];
#pragma unroll
    for (int j = 0; j < 8; ++j) o[j] = 0.f;
#pragma unroll
    for (int kvh = 0; kvh < 4; ++kvh) {
      const int blk = b + 8 * kvh + 32 * qt;
      wsum += Sl[blk * 128 + ql];
      bf16x8 v = *(const bf16x8*)(Opart + ((size_t)blk * 128 + ql) * 256 + lane2 * 8);
#pragma unroll
      for (int j = 0; j < 8; ++j) o[j] += (float)v[j];
    }
    const float inv = 1.f / wsum;
#pragma unroll
    for (int j = 0; j < 8; ++j) Ocomb[qq][lane2 * 8 + j] = o[j] * inv;
  }
  __syncthreads();
  const int q = t & 31;
  const int dbase = (t >> 5) * 32;
#pragma unroll
  for (int j = 0; j < 32; ++j) {
    const int d = dbase + j;
    Hb[(size_t)d * 2048 + q] = Ocomb[q][d];
  }
}

extern "C" void kernel_launch(void* const* d_in, const int* in_sizes, int n_in,
                              void* d_out, int out_size, void* d_ws, size_t ws_size,
                              hipStream_t stream) {
  (void)in_sizes; (void)n_in; (void)out_size; (void)ws_size;
  const float* x = (const float*)d_in[0];
  const float* Wq = (const float*)d_in[1];
  const float* bq = (const float*)d_in[2];
  const float* Wk = (const float*)d_in[3];
  const float* bk = (const float*)d_in[4];
  const float* Wv = (const float*)d_in[5];
  const float* bv = (const float*)d_in[6];
  char* ws = (char*)d_ws;
  bf16* xT = (bf16*)(ws + 0);                 // 8,396,800
  bf16* W2 = (bf16*)(ws + 8396800);           // 1,179,648
  float* biasA = (float*)(ws + 9576448);      // 3,072 (+pad)
  bf16* QT = (bf16*)(ws + 9580544);           // 8,388,608
  bf16* KT = (bf16*)(ws + 17969152);          // 8,388,608
  bf16* V = (bf16*)(ws + 26357760);           // 8,388,608
  bf16* Opart = (bf16*)(ws + 34746368);       // 512*128*256*2 = 33,554,432
  float* Sl = (float*)(ws + 68300800);        // 262,144
  float* H = (float*)d_out;

  prep_w<<<dim3(2304), dim3(256), 0, stream>>>(Wq, Wk, Wv, bq, bk, bv, W2, biasA);
  prep_x<<<dim3(2048), dim3(256), 0, stream>>>(x, xT);
  conv_gemm<<<dim3(768), dim3(256), 0, stream>>>(W2, xT, biasA, QT, KT, V);
  attn<<<dim3(512), dim3(256), 0, stream>>>(QT, KT, V, Opart, Sl);
  merge_p<<<dim3(512), dim3(256), 0, stream>>>(Opart, Sl, H);
}

// Round 18
// 106.043 us; speedup vs baseline: 1.1108x; 1.0253x over previous
//
#include <hip/hip_runtime.h>
#include <hip/hip_bf16.h>
#include <stdint.h>

// B=8, C=256, L=2048, DK=DV=256, KS=3, PAD=1
// conv-QKV as GEMM (bf16 MFMA), flash attention with swapped QK^T.
// R18: R17 + prep_w/prep_x fused into one launch (independent work, branch on
// blockIdx) — saves one graph-node launch. attn/conv/merge verbatim R17
// (attn = best-measured R11 engine, 68.5us; conv at m97 plateau ~880 GF/s).

typedef __bf16 bf16;
typedef __bf16 bf16x2 __attribute__((ext_vector_type(2)));
typedef __bf16 bf16x4 __attribute__((ext_vector_type(4)));
typedef __bf16 bf16x8 __attribute__((ext_vector_type(8)));
typedef float f32x4 __attribute__((ext_vector_type(4)));
typedef uint32_t u32x4 __attribute__((ext_vector_type(4)));
typedef __attribute__((address_space(1))) const uint32_t cu32_as1;
typedef __attribute__((address_space(3))) uint32_t u32_as3;

#define DEVI __device__ __forceinline__
#define LOG2E 1.44269504088896f

DEVI void async_copy16(const void* g, void* l) {
  __builtin_amdgcn_global_load_lds((cu32_as1*)g, (u32_as3*)l, 16, 0, 0);
}

DEVI void block_sync() {
  asm volatile("" ::: "memory");
  __builtin_amdgcn_sched_barrier(0);
  __builtin_amdgcn_s_barrier();
  __builtin_amdgcn_sched_barrier(0);
  asm volatile("" ::: "memory");
}

#define VMCNT(n) asm volatile("s_waitcnt vmcnt(" #n ")" ::: "memory")

// ---------------- fused prep: weights+bias (blocks 0..2303) | x-transpose (2304..4351) ----
// prep_w part: W2[o][ks*256+c] = W[o][c][ks] bf16, Q rows scaled by QSC.
// prep_x part: xTpad[b][l+1][c] bf16 via 64c x 32l LDS tile, both sides coalesced.
__global__ void prep_wx(const float* __restrict__ Wq, const float* __restrict__ Wk,
                        const float* __restrict__ Wv, const float* __restrict__ bq,
                        const float* __restrict__ bk, const float* __restrict__ bv,
                        bf16* __restrict__ W2, float* __restrict__ biasA,
                        const float* __restrict__ x, bf16* __restrict__ xT) {
  __shared__ float tile[64][33];
  const int blk = blockIdx.x;
  const int t = threadIdx.x;
  if (blk < 2304) {
    const float QSC = 0.0625f * LOG2E;
    int idx = blk * 256 + t;
    if (idx < 768 * 768) {
      int o = idx / 768, kk = idx - o * 768;
      int ks = kk >> 8, c = kk & 255;
      const float* W = (o < 256) ? Wq : ((o < 512) ? Wk : Wv);
      int ol = o & 255;
      float w = W[ol * 768 + c * 3 + ks];
      if (o < 256) w *= QSC;
      W2[o * 768 + kk] = (bf16)w;
    }
    if (idx < 768) {
      float v;
      if (idx < 256) v = bq[idx] * QSC;
      else if (idx < 512) v = bk[idx - 256];
      else v = bv[idx - 512];
      biasA[idx] = v;
    }
    return;
  }
  const int bid = blk - 2304;
  const int b = bid >> 8;
  const int rest = bid & 255;
  const int ct = rest & 3;
  const int lt = rest >> 2;
  const int c0 = ct * 64, l0 = lt * 32;
  const float* xb = x + (size_t)b * 256 * 2048;
#pragma unroll
  for (int i = 0; i < 8; ++i) {
    const int cc = (t >> 5) + i * 8;
    tile[cc][t & 31] = xb[(size_t)(c0 + cc) * 2048 + l0 + (t & 31)];
  }
  __syncthreads();
  bf16* xTb = xT + (size_t)b * 2050 * 256;
#pragma unroll
  for (int j = 0; j < 8; ++j) {
    const int ll = (t >> 6) + j * 4;
    xTb[(size_t)(l0 + ll + 1) * 256 + c0 + (t & 63)] = (bf16)tile[t & 63][ll];
  }
  if (lt == 0 && t < 64) xTb[c0 + t] = (bf16)0.f;
  if (lt == 63 && t < 64) xTb[(size_t)2049 * 256 + c0 + t] = (bf16)0.f;
}

// ---------------- conv as MFMA GEMM (unchanged) ----------------
__launch_bounds__(256, 2)
__global__ void conv_gemm(const bf16* __restrict__ W2, const bf16* __restrict__ xT,
                          const float* __restrict__ biasA, bf16* __restrict__ QT,
                          bf16* __restrict__ KT, bf16* __restrict__ V) {
  __shared__ bf16 Alds[128 * 64];
  __shared__ bf16 Blds[128 * 64];
  const int t = threadIdx.x;
  const int w = t >> 6, lane = t & 63;
  const int g = lane >> 4, lr = lane & 15;
  const int wr = w >> 1, wc = w & 1;
  const int bid = blockIdx.x;
  const int b = bid & 7;
  const int rest = bid >> 3;
  const int ot = rest % 6;
  const int lt = rest / 6;
  const int l0 = lt * 128;

  const bf16* xTb = xT + (size_t)b * 2050 * 256;
  const bf16* Ab = W2 + (size_t)(ot * 128) * 768;

  const int srow = t >> 3;
  const int scb = ((t & 7) * 16) ^ ((srow & 7) << 4);

  f32x4 acc[4][4];
#pragma unroll
  for (int i = 0; i < 4; ++i)
#pragma unroll
    for (int j = 0; j < 4; ++j) acc[i][j] = (f32x4){0.f, 0.f, 0.f, 0.f};

  for (int step = 0; step < 12; ++step) {
    const int kk = step * 64;
    const int ks = kk >> 8;
    const int c0 = kk & 255;
    const bf16* As = Ab + kk + (scb >> 1);
    const bf16* Bs = xTb + (size_t)(l0 + ks) * 256 + c0 + (scb >> 1);
#pragma unroll
    for (int i = 0; i < 4; ++i) {
      const int row = srow + i * 32;
      async_copy16(As + (size_t)row * 768, (char*)Alds + w * 1024 + i * 4096);
      async_copy16(Bs + (size_t)row * 256, (char*)Blds + w * 1024 + i * 4096);
    }
    asm volatile("s_waitcnt vmcnt(0)" ::: "memory");
    __syncthreads();
#pragma unroll
    for (int sub = 0; sub < 2; ++sub) {
      bf16x8 af[4], bfr[4];
#pragma unroll
      for (int mf = 0; mf < 4; ++mf) {
        const int row = wr * 64 + mf * 16 + lr;
        const int cb = (sub * 64 + g * 16) ^ ((row & 7) << 4);
        af[mf] = *(const bf16x8*)((const char*)Alds + row * 128 + cb);
      }
#pragma unroll
      for (int nf = 0; nf < 4; ++nf) {
        const int row = wc * 64 + nf * 16 + lr;
        const int cb = (sub * 64 + g * 16) ^ ((row & 7) << 4);
        bfr[nf] = *(const bf16x8*)((const char*)Blds + row * 128 + cb);
      }
#pragma unroll
      for (int mf = 0; mf < 4; ++mf)
#pragma unroll
        for (int nf = 0; nf < 4; ++nf)
          acc[mf][nf] = __builtin_amdgcn_mfma_f32_16x16x32_bf16(af[mf], bfr[nf], acc[mf][nf], 0, 0, 0);
    }
    __syncthreads();
  }

  const int obase = ot * 128 + wr * 64;
  const int lbase = l0 + wc * 64;
  if (ot < 4) {
    bf16* dst = ((ot < 2) ? QT : KT) + (size_t)b * 2048 * 256;
#pragma unroll
    for (int mf = 0; mf < 4; ++mf) {
      const int og = obase + mf * 16 + g * 4;
      float bb[4];
#pragma unroll
      for (int r = 0; r < 4; ++r) bb[r] = biasA[og + r];
#pragma unroll
      for (int nf = 0; nf < 4; ++nf) {
        const int l = lbase + nf * 16 + lr;
        bf16x4 pk;
#pragma unroll
        for (int r = 0; r < 4; ++r) pk[r] = (bf16)(acc[mf][nf][r] + bb[r]);
        *(bf16x4*)(dst + (size_t)l * 256 + (og & 255)) = pk;
      }
    }
  } else {
    bf16* dst = V + (size_t)b * 256 * 2048;
#pragma unroll
    for (int mf = 0; mf < 4; ++mf) {
      const int og = obase + mf * 16 + g * 4;
      float bb[4];
#pragma unroll
      for (int r = 0; r < 4; ++r) bb[r] = biasA[og + r];
      const int ov = og - 512;
#pragma unroll
      for (int nf = 0; nf < 4; ++nf) {
        const int l = lbase + nf * 16 + lr;
#pragma unroll
        for (int r = 0; r < 4; ++r)
          dst[(size_t)(ov + r) * 2048 + l] = (bf16)(acc[mf][nf][r] + bb[r]);
      }
    }
  }
}

// ---------------- flash attention (R11 verbatim) ----------------
// 512 blocks = b(8) x kvh(4) x qt(16); 256 threads = 4 waves, wave owns 32 q.
// Keys [kvh*512 .. +512) in 16 tiles of 32. K double-buffered (staged 2 ahead),
// V single-buffered (staged 1 ahead). 2 barriers/kt. LDS 48KB.
// NOTE occupancy: VGPR_Count=128 excludes the 128 AGPRs of oacc[16][2] —
// true budget ~256 regs/wave -> 8 waves/CU cap (why LDS tweaks never helped).
__launch_bounds__(256, 2)
__global__ void attn(const bf16* __restrict__ QT, const bf16* __restrict__ KT,
                     const bf16* __restrict__ V, bf16* __restrict__ Opart,
                     float* __restrict__ Sl) {
  __shared__ bf16 Klds[2 * 32 * 256];   // 32 KB
  __shared__ bf16 Vlds[128 * 64];       // 16 KB (single buffer)
  const int t = threadIdx.x;
  const int w = t >> 6, lane = t & 63;
  const int g = lane >> 4, lr = lane & 15;
  const int bid = blockIdx.x;
  const int b = bid & 7;
  const int kvh = (bid >> 3) & 3;
  const int qt = bid >> 5;
  const int q0w = qt * 128 + w * 32;
  const int kb0 = kvh * 512;
  const bf16* QTb = QT + (size_t)b * 2048 * 256;
  const bf16* KTb = KT + (size_t)b * 2048 * 256;
  const bf16* Vb = V + (size_t)b * 256 * 2048;

  auto stageK = [&](int kt, int p) {
#pragma unroll
    for (int i = 0; i < 4; ++i) {
      const int row = i * 8 + (t >> 5);
      const int col = ((t & 31) ^ row) * 8;
      const bf16* src = KTb + (size_t)(kb0 + kt * 32 + row) * 256 + col;
      async_copy16(src, (char*)Klds + p * 16384 + i * 4096 + t * 16);
    }
  };
  auto stageV = [&](int kt) {
#pragma unroll
    for (int i = 0; i < 4; ++i) {
      const int row = i * 32 + (t >> 3);
      const int ls = (t & 7) ^ (row & 7);
      const int d = row * 2 + (ls >> 2);
      const int k0 = (ls & 3) * 8;
      const bf16* src = Vb + (size_t)d * 2048 + kb0 + kt * 32 + k0;
      async_copy16(src, (char*)Vlds + i * 4096 + t * 16);
    }
  };

  // Q in registers: q = q0w + qfr*16 + lr, d-chunk = ds*32 + g*8
  bf16x8 qreg[2][8];
#pragma unroll
  for (int qfr = 0; qfr < 2; ++qfr)
#pragma unroll
    for (int ds = 0; ds < 8; ++ds)
      qreg[qfr][ds] = *(const bf16x8*)(QTb + (size_t)(q0w + qfr * 16 + lr) * 256 + ds * 32 + g * 8);

  f32x4 oacc[16][2];
#pragma unroll
  for (int i = 0; i < 16; ++i) {
    oacc[i][0] = (f32x4){0.f, 0.f, 0.f, 0.f};
    oacc[i][1] = (f32x4){0.f, 0.f, 0.f, 0.f};
  }
  float l_acc[2] = {0.f, 0.f};   // lane-local partial softmax denominators

  // prologue: V(0) first, then K(0), K(1)  (issue order matters for VMCNT)
  stageV(0);
  stageK(0, 0);
  stageK(1, 1);

  for (int kt = 0; kt < 16; ++kt) {
    const int p = kt & 1;
    if (kt == 15) { VMCNT(0); } else { VMCNT(4); }  // K(kt), V(kt) landed
    block_sync();                                    // A: everyone's tile kt landed

    // ---- QK^T (swapped): sT[kfr][qfr] = S[k = kt*32+kfr*16+g*4+r][q = qfr*16+lr]
    f32x4 sT[2][2];
#pragma unroll
    for (int kfr = 0; kfr < 2; ++kfr)
#pragma unroll
      for (int qfr = 0; qfr < 2; ++qfr) sT[kfr][qfr] = (f32x4){0.f, 0.f, 0.f, 0.f};
    __builtin_amdgcn_s_setprio(1);
#pragma unroll
    for (int ds = 0; ds < 8; ++ds) {
      bf16x8 kf[2];
#pragma unroll
      for (int kfr = 0; kfr < 2; ++kfr) {
        const int row = kfr * 16 + lr;
        kf[kfr] = *(const bf16x8*)((const char*)Klds + p * 16384 + row * 512 +
                                   (((ds * 4 + g) ^ row) * 16));
      }
#pragma unroll
      for (int kfr = 0; kfr < 2; ++kfr)
#pragma unroll
        for (int qfr = 0; qfr < 2; ++qfr)
          sT[kfr][qfr] = __builtin_amdgcn_mfma_f32_16x16x32_bf16(kf[kfr], qreg[qfr][ds], sT[kfr][qfr], 0, 0, 0);
    }
    __builtin_amdgcn_s_setprio(0);

    // ---- P = exp2(S) (no max-stabilization; lane-local l accumulation)
#pragma unroll
    for (int kfr = 0; kfr < 2; ++kfr)
#pragma unroll
      for (int qfr = 0; qfr < 2; ++qfr)
#pragma unroll
        for (int r = 0; r < 4; ++r) {
          float pe = __builtin_exp2f(sT[kfr][qfr][r]);
          sT[kfr][qfr][r] = pe;
          l_acc[qfr] += pe;
        }

    // ---- P route to PV B-operand (in-register, per qfr)
    bf16x8 pB[2];
#pragma unroll
    for (int qfr = 0; qfr < 2; ++qfr) {
      uint32_t wq[2][2];
#pragma unroll
      for (int kfr = 0; kfr < 2; ++kfr)
#pragma unroll
        for (int pp = 0; pp < 2; ++pp) {
          bf16x2 pr;
          pr[0] = (bf16)sT[kfr][qfr][2 * pp];
          pr[1] = (bf16)sT[kfr][qfr][2 * pp + 1];
          wq[kfr][pp] = __builtin_bit_cast(uint32_t, pr);
        }
      uint32_t bw[4];
#pragma unroll
      for (int j = 0; j < 4; ++j) {
        const int srcLane = ((g & 1) * 2 + (j >> 1)) * 16 + lr;
        const uint32_t a = (uint32_t)__shfl((int)wq[0][j & 1], srcLane, 64);
        const uint32_t bb = (uint32_t)__shfl((int)wq[1][j & 1], srcLane, 64);
        bw[j] = (lane < 32) ? a : bb;
      }
      u32x4 v4 = {bw[0], bw[1], bw[2], bw[3]};
      pB[qfr] = __builtin_bit_cast(bf16x8, v4);
    }

    // ---- PV: oacc[dfr][qfr] += V[d][k] * P[k][q]
    __builtin_amdgcn_s_setprio(1);
#pragma unroll
    for (int dfr = 0; dfr < 16; ++dfr) {
      const int row = dfr * 8 + (lr >> 1);
      bf16x8 vf = *(const bf16x8*)((const char*)Vlds + row * 128 +
                                   ((((lr & 1) * 4 + g) ^ ((lr >> 1) & 7)) * 16));
      oacc[dfr][0] = __builtin_amdgcn_mfma_f32_16x16x32_bf16(vf, pB[0], oacc[dfr][0], 0, 0, 0);
      oacc[dfr][1] = __builtin_amdgcn_mfma_f32_16x16x32_bf16(vf, pB[1], oacc[dfr][1], 0, 0, 0);
    }
    __builtin_amdgcn_s_setprio(0);
    block_sync();                       // B: all waves done reading Klds[p], Vlds
    if (kt < 15) stageV(kt + 1);        // V(kt+1) hidden under next QK+softmax
    if (kt < 14) stageK(kt + 2, p);     // K(kt+2) into freed buffer p
  }

  // ---- epilogue: reduce l across the 4 k-groups (lanes lr, lr+16, lr+32, lr+48)
#pragma unroll
  for (int qfr = 0; qfr < 2; ++qfr) {
    float rv = l_acc[qfr];
    rv += __shfl_xor(rv, 16, 64);
    rv += __shfl_xor(rv, 32, 64);
    l_acc[qfr] = rv;
  }

  // ---- store partial O (bf16, [q][d]) + l
  bf16* Op = Opart + (size_t)bid * 128 * 256;
#pragma unroll
  for (int qfr = 0; qfr < 2; ++qfr) {
    const int ql = w * 32 + qfr * 16 + lr;
#pragma unroll
    for (int dfr = 0; dfr < 16; ++dfr) {
      const int d0 = dfr * 16 + g * 4;
      bf16x4 pk;
#pragma unroll
      for (int r = 0; r < 4; ++r) pk[r] = (bf16)oacc[dfr][qfr][r];
      *(bf16x4*)(Op + (size_t)ql * 256 + d0) = pk;
    }
    if (g == 0) Sl[bid * 128 + ql] = l_acc[qfr];
  }
}

// ---------------- merge 4 KV-split partials -> H (vectorized, coalesced) ----------------
__launch_bounds__(256)
__global__ void merge_p(const bf16* __restrict__ Opart, const float* __restrict__ Sl,
                        float* __restrict__ H) {
  __shared__ float Ocomb[32][257];
  const int bid = blockIdx.x;
  const int b = bid & 7;
  const int qt = (bid >> 3) & 15;
  const int qc = bid >> 7;
  const int t = threadIdx.x;
  const int g2 = t >> 5, lane2 = t & 31;
  float* Hb = H + (size_t)b * 256 * 2048 + qt * 128 + qc * 32;

#pragma unroll
  for (int qb = 0; qb < 4; ++qb) {
    const int qq = qb * 8 + g2;
    const int ql = qc * 32 + qq;
    float wsum = 0.f;
    float o[8];
#pragma unroll
    for (int j = 0; j < 8; ++j) o[j] = 0.f;
#pragma unroll
    for (int kvh = 0; kvh < 4; ++kvh) {
      const int blk = b + 8 * kvh + 32 * qt;
      wsum += Sl[blk * 128 + ql];
      bf16x8 v = *(const bf16x8*)(Opart + ((size_t)blk * 128 + ql) * 256 + lane2 * 8);
#pragma unroll
      for (int j = 0; j < 8; ++j) o[j] += (float)v[j];
    }
    const float inv = 1.f / wsum;
#pragma unroll
    for (int j = 0; j < 8; ++j) Ocomb[qq][lane2 * 8 + j] = o[j] * inv;
  }
  __syncthreads();
  const int q = t & 31;
  const int dbase = (t >> 5) * 32;
#pragma unroll
  for (int j = 0; j < 32; ++j) {
    const int d = dbase + j;
    Hb[(size_t)d * 2048 + q] = Ocomb[q][d];
  }
}

extern "C" void kernel_launch(void* const* d_in, const int* in_sizes, int n_in,
                              void* d_out, int out_size, void* d_ws, size_t ws_size,
                              hipStream_t stream) {
  (void)in_sizes; (void)n_in; (void)out_size; (void)ws_size;
  const float* x = (const float*)d_in[0];
  const float* Wq = (const float*)d_in[1];
  const float* bq = (const float*)d_in[2];
  const float* Wk = (const float*)d_in[3];
  const float* bk = (const float*)d_in[4];
  const float* Wv = (const float*)d_in[5];
  const float* bv = (const float*)d_in[6];
  char* ws = (char*)d_ws;
  bf16* xT = (bf16*)(ws + 0);                 // 8,396,800
  bf16* W2 = (bf16*)(ws + 8396800);           // 1,179,648
  float* biasA = (float*)(ws + 9576448);      // 3,072 (+pad)
  bf16* QT = (bf16*)(ws + 9580544);           // 8,388,608
  bf16* KT = (bf16*)(ws + 17969152);          // 8,388,608
  bf16* V = (bf16*)(ws + 26357760);           // 8,388,608
  bf16* Opart = (bf16*)(ws + 34746368);       // 512*128*256*2 = 33,554,432
  float* Sl = (float*)(ws + 68300800);        // 262,144
  float* H = (float*)d_out;

  prep_wx<<<dim3(4352), dim3(256), 0, stream>>>(Wq, Wk, Wv, bq, bk, bv, W2, biasA, x, xT);
  conv_gemm<<<dim3(768), dim3(256), 0, stream>>>(W2, xT, biasA, QT, KT, V);
  attn<<<dim3(512), dim3(256), 0, stream>>>(QT, KT, V, Opart, Sl);
  merge_p<<<dim3(512), dim3(256), 0, stream>>>(Opart, Sl, H);
}